// Round 1
// baseline (984.523 us; speedup 1.0000x reference)
//
#include <hip/hip_runtime.h>
#include <math.h>

// FastRPModel, two-phase:
//   Phase 1 (streaming): emb[n,d] = sum_{p,k} softmax_k(fw)[p,k] * feats[p,k,n,d]
//                        -> 64 MB table in workspace. Read 768 MB + write 64 MB,
//                        fully coalesced float4 streams (~135 us at 6.3 TB/s).
//   Phase 2 (gather):    out[e] = sigmoid(intercept - ||emb[i]-emb[j]||^2 / D)
//                        emb table (64 MB) fits in 256 MB L3 -> gathers are cache hits.
// Replaces the fused gather design whose 423 MB unique scattered working set
// overflowed L3 and ran at ~0.7 TB/s.

constexpr int Pp = 4;
constexpr int Kk = 3;
constexpr int Nn = 250000;
constexpr int Dd = 64;
constexpr int PK = Pp * Kk;

__device__ __forceinline__ void softmax_weights(const float* __restrict__ fw,
                                                float* __restrict__ w) {
    #pragma unroll
    for (int p = 0; p < Pp; ++p) {
        float e[Kk];
        float m = -INFINITY;
        #pragma unroll
        for (int k = 0; k < Kk; ++k) {
            e[k] = fw[p * Kk + k];
            m = fmaxf(m, e[k]);
        }
        float s = 0.0f;
        #pragma unroll
        for (int k = 0; k < Kk; ++k) {
            e[k] = __expf(e[k] - m);
            s += e[k];
        }
        const float inv = 1.0f / s;
        #pragma unroll
        for (int k = 0; k < Kk; ++k) w[p * Kk + k] = e[k] * inv;
    }
}

// ---------------- Phase 1: streaming contraction over (p,k) ----------------
__global__ __launch_bounds__(256) void fastrp_emb_kernel(
    const float* __restrict__ feats,  // [P,K,N,D]
    const float* __restrict__ fw,     // [P,K]
    float*       __restrict__ emb,    // [N,D] workspace
    int total4)                       // N*D/4
{
    float w[PK];
    softmax_weights(fw, w);  // fw address is wave-uniform -> scalar loads, L1-hot

    const int stride = gridDim.x * blockDim.x;
    for (int v = blockIdx.x * blockDim.x + threadIdx.x; v < total4; v += stride) {
        float4 acc = make_float4(0.0f, 0.0f, 0.0f, 0.0f);
        #pragma unroll
        for (int pk = 0; pk < PK; ++pk) {
            const float4* src =
                reinterpret_cast<const float4*>(feats + (size_t)pk * Nn * Dd);
            const float4 f = src[v];
            acc.x = fmaf(w[pk], f.x, acc.x);
            acc.y = fmaf(w[pk], f.y, acc.y);
            acc.z = fmaf(w[pk], f.z, acc.z);
            acc.w = fmaf(w[pk], f.w, acc.w);
        }
        reinterpret_cast<float4*>(emb)[v] = acc;
    }
}

// ---------------- Phase 2: edge gather from L3-resident table ----------------
// 16 lanes per edge, float4 per lane (256 B per row in one instruction-group).
__global__ __launch_bounds__(256) void fastrp_edge_from_emb(
    const float* __restrict__ emb,        // [N,D]
    const float* __restrict__ intercept,  // [1]
    const int*   __restrict__ idx_i,      // [E]
    const int*   __restrict__ idx_j,      // [E]
    float*       __restrict__ out,        // [E]
    int E)
{
    const int tid  = (int)(blockIdx.x * blockDim.x + threadIdx.x);
    const int lane = threadIdx.x & 63;
    const int q    = lane & 15;   // sub-lane within edge: dims [q*4, q*4+3]
    const int e    = tid >> 4;    // 16 lanes per edge
    if (e >= E) return;           // uniform across each 16-lane group

    const long long i = (long long)idx_i[e];
    const long long j = (long long)idx_j[e];

    const float4 zi = *reinterpret_cast<const float4*>(emb + i * Dd + q * 4);
    const float4 zj = *reinterpret_cast<const float4*>(emb + j * Dd + q * 4);

    const float dx = zi.x - zj.x;
    const float dy = zi.y - zj.y;
    const float dz = zi.z - zj.z;
    const float dw = zi.w - zj.w;
    float v = dx * dx + dy * dy + dz * dz + dw * dw;

    // reduce within the 16-lane group (xor masks < 16 stay inside the group)
    v += __shfl_xor(v, 1, 64);
    v += __shfl_xor(v, 2, 64);
    v += __shfl_xor(v, 4, 64);
    v += __shfl_xor(v, 8, 64);

    if (q == 0) {
        const float logit = intercept[0] - v * (1.0f / Dd);
        out[e] = 1.0f / (1.0f + __expf(-logit));
    }
}

// ---------------- Fallback: previous fused gather kernel ----------------
__global__ __launch_bounds__(256) void fastrp_edge_kernel(
    const float* __restrict__ feats, const float* __restrict__ fw,
    const float* __restrict__ intercept, const int* __restrict__ idx_i,
    const int* __restrict__ idx_j, float* __restrict__ out, int E)
{
    const int wave = (int)((blockIdx.x * (size_t)blockDim.x + threadIdx.x) >> 6);
    const int lane = threadIdx.x & 63;
    if (wave >= E) return;

    float w[PK];
    softmax_weights(fw, w);

    const long long i = (long long)idx_i[wave];
    const long long j = (long long)idx_j[wave];

    float zi = 0.0f, zj = 0.0f;
    #pragma unroll
    for (int pk = 0; pk < PK; ++pk) {
        const float* base = feats + (size_t)pk * Nn * Dd;
        zi = fmaf(w[pk], base[i * Dd + lane], zi);
        zj = fmaf(w[pk], base[j * Dd + lane], zj);
    }

    float diff = zi - zj;
    float v = diff * diff;
    #pragma unroll
    for (int off = 32; off > 0; off >>= 1) v += __shfl_xor(v, off, 64);

    if (lane == 0) {
        const float logit = intercept[0] - v * (1.0f / Dd);
        out[wave] = 1.0f / (1.0f + __expf(-logit));
    }
}

extern "C" void kernel_launch(void* const* d_in, const int* in_sizes, int n_in,
                              void* d_out, int out_size, void* d_ws, size_t ws_size,
                              hipStream_t stream) {
    const float* feats     = (const float*)d_in[0];
    const float* fw        = (const float*)d_in[1];
    const float* intercept = (const float*)d_in[2];
    const int*   idx_i     = (const int*)d_in[3];
    const int*   idx_j     = (const int*)d_in[4];
    float*       out       = (float*)d_out;

    const int E = in_sizes[3];
    const size_t emb_bytes = (size_t)Nn * Dd * sizeof(float);  // 64 MB

    if (ws_size >= emb_bytes) {
        float* emb = (float*)d_ws;

        // Phase 1: streaming contraction (memory-bound; ~2048 blocks, grid-stride)
        const int total4 = Nn * Dd / 4;  // 4,000,000 float4s
        const int block1 = 256;
        const int grid1  = 2048;
        fastrp_emb_kernel<<<grid1, block1, 0, stream>>>(feats, fw, emb, total4);

        // Phase 2: edge gather (same stream -> ordered after phase 1)
        const int block2 = 256;                    // 16 edges per block
        const int edges_per_block = block2 / 16;
        const int grid2 = (E + edges_per_block - 1) / edges_per_block;
        fastrp_edge_from_emb<<<grid2, block2, 0, stream>>>(emb, intercept,
                                                           idx_i, idx_j, out, E);
    } else {
        // Workspace too small: fall back to the fused single-pass kernel.
        const int block = 256;
        const int waves_per_block = block / 64;
        const int grid = (E + waves_per_block - 1) / waves_per_block;
        fastrp_edge_kernel<<<grid, block, 0, stream>>>(feats, fw, intercept,
                                                       idx_i, idx_j, out, E);
    }
}

// Round 2
// 924.603 us; speedup vs baseline: 1.0648x; 1.0648x over previous
//
#include <hip/hip_runtime.h>
#include <math.h>

// FastRPModel, two-phase with touched-node filtering:
//   Pass 0a: zero 31 KB node bitmap (in workspace).
//   Pass 0b: scatter idx_i/idx_j into bitmap via atomicOr (~15 us).
//   Pass 1 : emb[n,:] = sum_pk softmax(fw)[pk] * feats[pk,n,:]  -- ONLY for
//            touched nodes (~55% of 250k). 16 lanes per node row, float4/lane;
//            untouched rows are skipped at 256 B granularity via exec-masked
//            16-lane groups, cutting feats DRAM fetch ~832 MB -> ~460 MB.
//   Pass 2 : out[e] = sigmoid(intercept - ||emb[i]-emb[j]||^2 / D); emb rows
//            for touched nodes are L2/L3-resident (<= 35 MB written).
// Evidence basis: every feats-streaming kernel so far runs at ~1.7-1.8 TB/s
// effective, so bytes-read is the controllable lever; untouched rows are 45%.

constexpr int Pp = 4;
constexpr int Kk = 3;
constexpr int Nn = 250000;
constexpr int Dd = 64;
constexpr int PK = Pp * Kk;
constexpr int BM_WORDS = (Nn + 31) / 32;  // 7813 words = 31.25 KB

typedef float v4f __attribute__((ext_vector_type(4)));

__device__ __forceinline__ void softmax_weights(const float* __restrict__ fw,
                                                float* __restrict__ w) {
    #pragma unroll
    for (int p = 0; p < Pp; ++p) {
        float e[Kk];
        float m = -INFINITY;
        #pragma unroll
        for (int k = 0; k < Kk; ++k) {
            e[k] = fw[p * Kk + k];
            m = fmaxf(m, e[k]);
        }
        float s = 0.0f;
        #pragma unroll
        for (int k = 0; k < Kk; ++k) {
            e[k] = __expf(e[k] - m);
            s += e[k];
        }
        const float inv = 1.0f / s;
        #pragma unroll
        for (int k = 0; k < Kk; ++k) w[p * Kk + k] = e[k] * inv;
    }
}

// ---------------- Pass 0a: zero the bitmap (workspace is poisoned each iter) --
__global__ __launch_bounds__(256) void bm_zero(unsigned int* __restrict__ bm) {
    const int t = blockIdx.x * blockDim.x + threadIdx.x;
    if (t < BM_WORDS) bm[t] = 0u;
}

// ---------------- Pass 0b: mark touched nodes ----------------
__global__ __launch_bounds__(256) void bm_build(const int* __restrict__ idx_i,
                                                const int* __restrict__ idx_j,
                                                unsigned int* __restrict__ bm,
                                                int E) {
    const int t = blockIdx.x * blockDim.x + threadIdx.x;
    if (t >= E) return;
    const int a = idx_i[t];
    const int b = idx_j[t];
    atomicOr(&bm[a >> 5], 1u << (a & 31));
    atomicOr(&bm[b >> 5], 1u << (b & 31));
}

// ---------------- Pass 1: contraction for touched rows only ----------------
// thread t -> node n = t>>4, row-slot q = t&15 (dims q*4..q*4+3).
__global__ __launch_bounds__(256) void fastrp_emb_touched(
    const float* __restrict__ feats,        // [P,K,N,D]
    const float* __restrict__ fw,           // [P,K]
    const unsigned int* __restrict__ bm,    // [BM_WORDS]
    float*       __restrict__ emb)          // [N,D] workspace
{
    const int t = blockIdx.x * blockDim.x + threadIdx.x;
    const int n = t >> 4;
    const int q = t & 15;
    if (n >= Nn) return;
    if (!((bm[n >> 5] >> (n & 31)) & 1u)) return;  // group-uniform: 256B skip

    float w[PK];
    softmax_weights(fw, w);  // uniform scalar loads, L1-hot

    const size_t off = (size_t)n * Dd + q * 4;
    v4f acc = 0.0f;
    #pragma unroll
    for (int pk = 0; pk < PK; ++pk) {
        const v4f f = *reinterpret_cast<const v4f*>(feats + (size_t)pk * Nn * Dd + off);
        acc.x = fmaf(w[pk], f.x, acc.x);
        acc.y = fmaf(w[pk], f.y, acc.y);
        acc.z = fmaf(w[pk], f.z, acc.z);
        acc.w = fmaf(w[pk], f.w, acc.w);
    }
    *reinterpret_cast<v4f*>(emb + off) = acc;
}

// ---------------- Pass 2: edge gather from cached table ----------------
__global__ __launch_bounds__(256) void fastrp_edge_from_emb(
    const float* __restrict__ emb,        // [N,D]
    const float* __restrict__ intercept,  // [1]
    const int*   __restrict__ idx_i,      // [E]
    const int*   __restrict__ idx_j,      // [E]
    float*       __restrict__ out,        // [E]
    int E)
{
    const int tid  = (int)(blockIdx.x * blockDim.x + threadIdx.x);
    const int q    = threadIdx.x & 15;
    const int e    = tid >> 4;
    if (e >= E) return;

    const long long i = (long long)idx_i[e];
    const long long j = (long long)idx_j[e];

    const float4 zi = *reinterpret_cast<const float4*>(emb + i * Dd + q * 4);
    const float4 zj = *reinterpret_cast<const float4*>(emb + j * Dd + q * 4);

    const float dx = zi.x - zj.x;
    const float dy = zi.y - zj.y;
    const float dz = zi.z - zj.z;
    const float dw = zi.w - zj.w;
    float v = dx * dx + dy * dy + dz * dz + dw * dw;

    v += __shfl_xor(v, 1, 64);
    v += __shfl_xor(v, 2, 64);
    v += __shfl_xor(v, 4, 64);
    v += __shfl_xor(v, 8, 64);

    if (q == 0) {
        const float logit = intercept[0] - v * (1.0f / Dd);
        out[e] = 1.0f / (1.0f + __expf(-logit));
    }
}

// ---------------- Fallback: fused single-pass kernel (small workspace) ------
__global__ __launch_bounds__(256) void fastrp_edge_kernel(
    const float* __restrict__ feats, const float* __restrict__ fw,
    const float* __restrict__ intercept, const int* __restrict__ idx_i,
    const int* __restrict__ idx_j, float* __restrict__ out, int E)
{
    const int wave = (int)((blockIdx.x * (size_t)blockDim.x + threadIdx.x) >> 6);
    const int lane = threadIdx.x & 63;
    if (wave >= E) return;

    float w[PK];
    softmax_weights(fw, w);

    const long long i = (long long)idx_i[wave];
    const long long j = (long long)idx_j[wave];

    float zi = 0.0f, zj = 0.0f;
    #pragma unroll
    for (int pk = 0; pk < PK; ++pk) {
        const float* base = feats + (size_t)pk * Nn * Dd;
        zi = fmaf(w[pk], base[i * Dd + lane], zi);
        zj = fmaf(w[pk], base[j * Dd + lane], zj);
    }

    float diff = zi - zj;
    float v = diff * diff;
    #pragma unroll
    for (int off = 32; off > 0; off >>= 1) v += __shfl_xor(v, off, 64);

    if (lane == 0) {
        const float logit = intercept[0] - v * (1.0f / Dd);
        out[wave] = 1.0f / (1.0f + __expf(-logit));
    }
}

extern "C" void kernel_launch(void* const* d_in, const int* in_sizes, int n_in,
                              void* d_out, int out_size, void* d_ws, size_t ws_size,
                              hipStream_t stream) {
    const float* feats     = (const float*)d_in[0];
    const float* fw        = (const float*)d_in[1];
    const float* intercept = (const float*)d_in[2];
    const int*   idx_i     = (const int*)d_in[3];
    const int*   idx_j     = (const int*)d_in[4];
    float*       out       = (float*)d_out;

    const int E = in_sizes[3];
    const size_t emb_bytes = (size_t)Nn * Dd * sizeof(float);       // 64 MB
    const size_t need = emb_bytes + (size_t)BM_WORDS * sizeof(unsigned int);

    if (ws_size >= need) {
        float* emb = (float*)d_ws;
        unsigned int* bm = (unsigned int*)((char*)d_ws + emb_bytes);

        // Pass 0: bitmap zero + build
        bm_zero<<<(BM_WORDS + 255) / 256, 256, 0, stream>>>(bm);
        bm_build<<<(E + 255) / 256, 256, 0, stream>>>(idx_i, idx_j, bm, E);

        // Pass 1: contraction, touched rows only (16 lanes per node row)
        const int threads1 = Nn * 16;  // 4,000,000
        fastrp_emb_touched<<<(threads1 + 255) / 256, 256, 0, stream>>>(
            feats, fw, bm, emb);

        // Pass 2: edge gather
        const int threads2 = E * 16;
        fastrp_edge_from_emb<<<(threads2 + 255) / 256, 256, 0, stream>>>(
            emb, intercept, idx_i, idx_j, out, E);
    } else {
        const int block = 256;
        const int grid = (E + block / 64 - 1) / (block / 64);
        fastrp_edge_kernel<<<grid, block, 0, stream>>>(feats, fw, intercept,
                                                       idx_i, idx_j, out, E);
    }
}